// Round 1
// 52.392 us; speedup vs baseline: 1.0973x; 1.0973x over previous
//
#include <hip/hip_runtime.h>
#include <hip/hip_bf16.h>

#define Bdim 4096
#define Ldim 4096
#define Hdim 1024
#define BM 256
#define BN 256
#define BK 64
#define NT (Hdim / BK)   // 16 K-tiles

typedef __attribute__((ext_vector_type(8))) __bf16 bf16x8;
typedef __attribute__((ext_vector_type(4))) float floatx4;

__device__ __forceinline__ unsigned short f2bf(float f) {
  union { __hip_bfloat16 h; unsigned short u; } c;
  c.h = __float2bfloat16(f);
  return c.u;
}

// ---- fused prep: blocks [0,Ldim) do W->bf16 + bias row; [Ldim,+Bdim) X->bf16
__global__ __launch_bounds__(256) void prep_kernel(
    const float* __restrict__ X, const float* __restrict__ E,
    const float* __restrict__ W, const float* __restrict__ b,
    unsigned short* __restrict__ Xb, unsigned short* __restrict__ Wb,
    float* __restrict__ bias) {
  const int blk = blockIdx.x;
  const int t = threadIdx.x;
  if (blk < Ldim) {
    const int row = blk;
    const float4 wv = reinterpret_cast<const float4*>(W + (size_t)row * Hdim)[t];
    const float4 ev = reinterpret_cast<const float4*>(E + (size_t)row * Hdim)[t];
    ushort4 o;
    o.x = f2bf(wv.x); o.y = f2bf(wv.y); o.z = f2bf(wv.z); o.w = f2bf(wv.w);
    reinterpret_cast<ushort4*>(Wb + (size_t)row * Hdim)[t] = o;
    float dot = wv.x * ev.x + wv.y * ev.y + wv.z * ev.z + wv.w * ev.w;
#pragma unroll
    for (int off = 32; off > 0; off >>= 1) dot += __shfl_down(dot, off, 64);
    __shared__ float part[4];
    if ((t & 63) == 0) part[t >> 6] = dot;
    __syncthreads();
    if (t == 0) bias[row] = part[0] + part[1] + part[2] + part[3] + b[row];
  } else {
    const int i = (blk - Ldim) * 256 + t;
    float4 v = reinterpret_cast<const float4*>(X)[i];
    ushort4 o;
    o.x = f2bf(v.x); o.y = f2bf(v.y); o.z = f2bf(v.z); o.w = f2bf(v.w);
    reinterpret_cast<ushort4*>(Xb)[i] = o;
  }
}

// ---- C[B,L] = Xb @ Wb^T + bias -----------------------------------------
// 256x256 tile, BK=64, 8 waves (2M x 4N, each owns 128x64 output).
// 4-phase/K-tile schedule (T3+T4): ds_reads front-loaded in ph1/ph2 so the
// read buffer is dead after ph2's barrier; ph4 stages tile t+2's A-half0
// into the freed buffer. Staging stream per tile t:
//   ph1 -> S(t+1, A-h1)  [buf c^1]
//   ph2 -> S(t+1, B-h0)  [buf c^1]
//   ph3 -> S(t+1, B-h1)  [buf c^1]
//   ph4 -> S(t+2, A-h0)  [buf c   -- safe: all reads of c done at ph2 barrier]
// vmcnt accounting (2 GLLs per stage, per wave): at tile-t ph1 the newest 4
// outstanding loads are S(t+1,A-h0) + S(t+1,A-h1) -> vmcnt(4) forces all of
// tile t complete; s_barrier extends to all waves. Never vmcnt(0) mid-loop.
// LDS swizzle (T2): logical k-slot ks (16B units) of row r stored at slot
// ks ^ (r&7). Write side stays linear (GLL requires it): the global SOURCE
// address is pre-swizzled per lane; for the GLL lane pattern row&7 == lane>>3,
// so src kslot = (lane&7) ^ (lane>>3). Read side applies the same XOR.
__global__ __launch_bounds__(512) void gemm_bias_kernel(
    const unsigned short* __restrict__ A,   // [Bdim][Hdim] bf16 bits
    const unsigned short* __restrict__ Bw,  // [Ldim][Hdim] bf16 bits
    const float* __restrict__ bias,         // [Ldim]
    float* __restrict__ C) {                // [Bdim][Ldim] fp32
  static_assert(NT >= 3, "pipeline needs >=3 K-tiles");
  __shared__ __align__(16) unsigned short lds[2][2][BM * BK];  // 128 KB

  const int tid = threadIdx.x;
  const int wave = tid >> 6;
  const int lane = tid & 63;
  const int wm = wave >> 2;   // 0..1  (M half)
  const int wn = wave & 3;    // 0..3  (N quarter)
  const int m_blk = blockIdx.y * BM;
  const int n_blk = blockIdx.x * BN;

  // staging source (pre-swizzled): wave covers rows [wave*8,+8) (+64 for 2nd GLL)
  const int srow = wave * 8 + (lane >> 3);
  const int skofs = ((lane & 7) ^ (lane >> 3)) * 8;
  const unsigned short* gA = A + (size_t)(m_blk + srow) * Hdim + skofs;
  const unsigned short* gB = Bw + (size_t)(n_blk + srow) * Hdim + skofs;

  // fragment read offsets (swizzled): row = base+fr, k 16B-slot = ksl*4+fq
  const int fr = lane & 15;
  const int fq = lane >> 4;
  const int kx0 = ((fq) ^ (fr & 7)) * 8;        // ksl=0
  const int kx1 = ((4 + fq) ^ (fr & 7)) * 8;    // ksl=1
  const int aBase = (wm * 128 + fr) * BK;
  const int bBase = (wn * 64 + fr) * BK;

  floatx4 acc[8][4] = {};
  bf16x8 af[8][2], bfv[4][2];

#define GLL(src, dst)                                                  \
  __builtin_amdgcn_global_load_lds(                                    \
      (const __attribute__((address_space(1))) void*)(src),            \
      (__attribute__((address_space(3))) void*)(dst), 16, 0, 0)

  // stage one half-tile (mat: 0=A 1=B, j: row-half) of K-tile kt into buf c
#define STAGE1(c, mat, j, kt)                                          \
  do {                                                                 \
    const unsigned short* _g = (mat) ? gB : gA;                        \
    GLL(_g + (size_t)((j) * 128) * Hdim + (size_t)(kt) * 64,           \
        &lds[c][mat][((j) * 128 + wave * 8) * BK]);                    \
    GLL(_g + (size_t)((j) * 128 + 64) * Hdim + (size_t)(kt) * 64,      \
        &lds[c][mat][((j) * 128 + 64 + wave * 8) * BK]);               \
  } while (0)

#define READ_R1(c)                                                     \
  do {                                                                 \
    _Pragma("unroll") for (int mi = 0; mi < 4; ++mi) {                 \
      af[mi][0] = *(const bf16x8*)&lds[c][0][aBase + mi * 16 * BK + kx0]; \
      af[mi][1] = *(const bf16x8*)&lds[c][0][aBase + mi * 16 * BK + kx1]; \
    }                                                                  \
    _Pragma("unroll") for (int ni = 0; ni < 2; ++ni) {                 \
      bfv[ni][0] = *(const bf16x8*)&lds[c][1][bBase + ni * 16 * BK + kx0]; \
      bfv[ni][1] = *(const bf16x8*)&lds[c][1][bBase + ni * 16 * BK + kx1]; \
    }                                                                  \
  } while (0)

#define READ_R2(c)                                                     \
  do {                                                                 \
    _Pragma("unroll") for (int mi = 4; mi < 8; ++mi) {                 \
      af[mi][0] = *(const bf16x8*)&lds[c][0][aBase + mi * 16 * BK + kx0]; \
      af[mi][1] = *(const bf16x8*)&lds[c][0][aBase + mi * 16 * BK + kx1]; \
    }                                                                  \
    _Pragma("unroll") for (int ni = 2; ni < 4; ++ni) {                 \
      bfv[ni][0] = *(const bf16x8*)&lds[c][1][bBase + ni * 16 * BK + kx0]; \
      bfv[ni][1] = *(const bf16x8*)&lds[c][1][bBase + ni * 16 * BK + kx1]; \
    }                                                                  \
  } while (0)

  // one C-quadrant (4 mi x 2 ni x 2 ksl = 16 MFMA), setprio-wrapped (T5)
#define MFMA_Q(M0, N0)                                                 \
  do {                                                                 \
    __builtin_amdgcn_s_setprio(1);                                     \
    _Pragma("unroll") for (int mi = (M0); mi < (M0) + 4; ++mi)         \
      _Pragma("unroll") for (int ni = (N0); ni < (N0) + 2; ++ni) {     \
        acc[mi][ni] = __builtin_amdgcn_mfma_f32_16x16x32_bf16(         \
            af[mi][0], bfv[ni][0], acc[mi][ni], 0, 0, 0);              \
        acc[mi][ni] = __builtin_amdgcn_mfma_f32_16x16x32_bf16(         \
            af[mi][1], bfv[ni][1], acc[mi][ni], 0, 0, 0);              \
      }                                                                \
    __builtin_amdgcn_s_setprio(0);                                     \
  } while (0)

  // prologue: tile 0 fully + tile 1 A-half0  (10 loads in flight)
  STAGE1(0, 0, 0, 0);
  STAGE1(0, 0, 1, 0);
  STAGE1(0, 1, 0, 0);
  STAGE1(0, 1, 1, 0);
  STAGE1(1, 0, 0, 1);

#pragma unroll 1
  for (int t = 0; t < NT - 1; ++t) {
    const int c = t & 1;
    // ---- ph1: issue S(t+1,A-h1) early, then gate on tile t complete
    STAGE1(c ^ 1, 0, 1, t + 1);
    asm volatile("s_waitcnt vmcnt(4)\n\ts_barrier" ::: "memory");
    READ_R1(c);
    MFMA_Q(0, 0);
    // ---- ph2
    STAGE1(c ^ 1, 1, 0, t + 1);
    READ_R2(c);
    MFMA_Q(4, 2);
    asm volatile("s_barrier" ::: "memory");  // all reads of buf c complete
    // ---- ph3 (pure MFMA + stage)
    STAGE1(c ^ 1, 1, 1, t + 1);
    MFMA_Q(0, 2);
    // ---- ph4: stage t+2's A-half0 into the freed buffer
    if (t < NT - 2) STAGE1(c, 0, 0, t + 2);
    MFMA_Q(4, 0);
  }

  // tail: tile NT-1 (buf (NT-1)&1 == 1), nothing left to stage
  asm volatile("s_waitcnt vmcnt(0)\n\ts_barrier" ::: "memory");
  READ_R1(1);
  READ_R2(1);
  MFMA_Q(0, 0);
  MFMA_Q(4, 2);
  MFMA_Q(0, 2);
  MFMA_Q(4, 0);

#undef GLL
#undef STAGE1
#undef READ_R1
#undef READ_R2
#undef MFMA_Q

  // epilogue: C/D layout col=lane&15, row=(lane>>4)*4+reg  [m89-verified]
  const int col0 = n_blk + wn * 64 + fr;
  const int row0 = m_blk + wm * 128 + fq * 4;
#pragma unroll
  for (int ni = 0; ni < 4; ++ni) {
    const float bs = bias[col0 + ni * 16];
#pragma unroll
    for (int mi = 0; mi < 8; ++mi) {
      float* cp = C + (size_t)(row0 + mi * 16) * Ldim + (col0 + ni * 16);
      floatx4 v = acc[mi][ni];
      cp[0 * (size_t)Ldim] = v.x + bs;
      cp[1 * (size_t)Ldim] = v.y + bs;
      cp[2 * (size_t)Ldim] = v.z + bs;
      cp[3 * (size_t)Ldim] = v.w + bs;
    }
  }
}

extern "C" void kernel_launch(void* const* d_in, const int* in_sizes, int n_in,
                              void* d_out, int out_size, void* d_ws, size_t ws_size,
                              hipStream_t stream) {
  const float* X = (const float*)d_in[0];  // bert_output [B,H]
  const float* E = (const float*)d_in[1];  // label_embed [L,H]
  const float* W = (const float*)d_in[2];  // W [L,H]
  const float* b = (const float*)d_in[3];  // b [L]
  // d_in[4] = labels, unused by the reference output.
  float* out = (float*)d_out;

  unsigned short* Xb = (unsigned short*)d_ws;                 // 8 MB
  unsigned short* Wb = Xb + (size_t)Bdim * Hdim;              // 8 MB
  float* bias = (float*)(Wb + (size_t)Ldim * Hdim);           // 16 KB

  prep_kernel<<<Ldim + Bdim, 256, 0, stream>>>(X, E, W, b, Xb, Wb, bias);
  dim3 grid(Ldim / BN, Bdim / BM);
  gemm_bias_kernel<<<grid, 512, 0, stream>>>(Xb, Wb, bias, out);
}